// Round 1
// baseline (103.384 us; speedup 1.0000x reference)
//
#include <hip/hip_runtime.h>

#define NAGENT 8192
#define NCELL 36
#define HIDDEN 128

// ---------------------------------------------------------------------------
// k1: pairwise occupancy histogram.
// Grid: 1024 blocks = 128 agent-groups (64 agents each) x 8 j-chunks (1024 js).
// Block: 256 threads = 4 waves. lane (tid&63) -> agent; wave (tid>>6) -> j subchunk
// of 256 js, wave-uniform j => obs[j] scalarizes to s_load_dwordx2.
// Private per-agent counter rows in LDS (64 x 36 u32), ds_add_u32 increments.
// Self-pair (j==i) is counted (rel==(3,3) exactly -> cell 21) and subtracted in k2.
// ---------------------------------------------------------------------------
__global__ __launch_bounds__(256) void occ_hist_kernel(
    const float2* __restrict__ obs, unsigned* __restrict__ occ) {
  __shared__ unsigned cnt[64 * NCELL];
  const int tid = threadIdx.x;
  for (int k = tid; k < 64 * NCELL; k += 256) cnt[k] = 0u;
  __syncthreads();

  const int ag   = blockIdx.x >> 3;  // 0..127 agent group
  const int jq   = blockIdx.x & 7;   // 0..7 j chunk
  const int lane = tid & 63;
  const int wv   = tid >> 6;         // 0..3
  const int agent = ag * 64 + lane;

  const float2 oi = obs[agent];
  const float xi = oi.x, yi = oi.y;

  unsigned* myCnt = &cnt[lane * NCELL];

  const int jbeg = jq * 1024 + wv * 256;
  const int jend = jbeg + 256;
#pragma unroll 4
  for (int j = jbeg; j < jend; ++j) {
    const float2 oj = obs[j];                 // wave-uniform -> s_load
    const float rx = (oj.x - xi) * 2.0f + 3.0f;
    const float ry = (oj.y - yi) * 2.0f + 3.0f;
    // float compares are NaN-safe (match reference's isnan masking for free)
    if (rx >= 0.0f && rx < 6.0f && ry >= 0.0f && ry < 6.0f) {
      const int cell = (int)rx * 6 + (int)ry; // rx,ry >= 0 -> trunc == floor
      atomicAdd(&myCnt[cell], 1u);            // ds_add_u32, private row
    }
  }
  __syncthreads();

  // combine partials across the 8 j-chunk blocks via global atomics
  unsigned* gbase = occ + (size_t)ag * 64 * NCELL;
  for (int k = tid; k < 64 * NCELL; k += 256) {
    const unsigned v = cnt[k];
    if (v) atomicAdd(&gbase[k], v);
  }
}

// ---------------------------------------------------------------------------
// k2: out[a,h] = b[h] + sum_c (occ[a,c] - self) * W[h,c]
// Grid: 512 blocks x 256 thr; 16 agents/block; thread = (agent, 8 h's).
// W staged in LDS (128x36 f32, rows = 9 float4, 144B stride: 16B-aligned and
// <=2-way bank aliasing). occ row in 36 regs. 288 FMA/thread.
// ---------------------------------------------------------------------------
__global__ __launch_bounds__(256) void occ_gemm_kernel(
    const unsigned* __restrict__ occ, const float* __restrict__ W,
    const float* __restrict__ bias, float* __restrict__ out) {
  __shared__ float Wl[HIDDEN * NCELL];
  const int tid = threadIdx.x;
  for (int k = tid; k < HIDDEN * NCELL; k += 256) Wl[k] = W[k];
  __syncthreads();

  const int a  = blockIdx.x * 16 + (tid >> 4);
  const int hg = tid & 15;

  const uint4* occ4 = (const uint4*)(occ + (size_t)a * NCELL);
  float occf[NCELL];
#pragma unroll
  for (int q = 0; q < 9; ++q) {
    const uint4 v = occ4[q];
    occf[4 * q + 0] = (float)v.x;
    occf[4 * q + 1] = (float)v.y;
    occf[4 * q + 2] = (float)v.z;
    occf[4 * q + 3] = (float)v.w;
  }
  occf[21] -= 1.0f;  // remove self-pair (cell 3*6+3)

  float acc[8];
#pragma unroll
  for (int k = 0; k < 8; ++k) acc[k] = bias[hg + 16 * k];

#pragma unroll
  for (int c4 = 0; c4 < 9; ++c4) {
#pragma unroll
    for (int k = 0; k < 8; ++k) {
      const float4 w4 = *(const float4*)&Wl[(hg + 16 * k) * NCELL + c4 * 4];
      acc[k] = fmaf(occf[4 * c4 + 0], w4.x, acc[k]);
      acc[k] = fmaf(occf[4 * c4 + 1], w4.y, acc[k]);
      acc[k] = fmaf(occf[4 * c4 + 2], w4.z, acc[k]);
      acc[k] = fmaf(occf[4 * c4 + 3], w4.w, acc[k]);
    }
  }

  float* ob = out + (size_t)a * HIDDEN;
#pragma unroll
  for (int k = 0; k < 8; ++k) ob[hg + 16 * k] = acc[k];
}

extern "C" void kernel_launch(void* const* d_in, const int* in_sizes, int n_in,
                              void* d_out, int out_size, void* d_ws, size_t ws_size,
                              hipStream_t stream) {
  (void)in_sizes; (void)n_in; (void)out_size; (void)ws_size;
  const float2* obs = (const float2*)d_in[0];
  const float*  W   = (const float*)d_in[1];
  const float*  b   = (const float*)d_in[2];
  float* out = (float*)d_out;
  unsigned* occ = (unsigned*)d_ws;  // 8192*36 u32 = 1.18 MB partial-count buffer

  // ws is poisoned 0xAA before every launch: zero the occupancy accumulator.
  hipMemsetAsync(occ, 0, (size_t)NAGENT * NCELL * sizeof(unsigned), stream);

  occ_hist_kernel<<<dim3(1024), dim3(256), 0, stream>>>(obs, occ);
  occ_gemm_kernel<<<dim3(512), dim3(256), 0, stream>>>(occ, W, b, out);
}

// Round 2
// 98.381 us; speedup vs baseline: 1.0509x; 1.0509x over previous
//
#include <hip/hip_runtime.h>

#define NAGENT 8192
#define NCELL 36
#define HIDDEN 128
#define CSTRIDE 37   // LDS counter row stride: gcd(37,32)=1 -> 2 lanes/bank (free)
#define PWORDS 18    // packed row: 36 cells as 18 u32 (2 x u16)

// ---------------------------------------------------------------------------
// k1: pairwise occupancy histogram, private partials, NO atomics to global.
// Grid: dim3(nchunk, 128). blockIdx.y = agent group (64 agents, lane=agent),
// blockIdx.x = j-chunk. 256 thr = 4 waves; wave wv scans jrange/4 js for all
// 64 agents (j wave-uniform -> obs[j] float4 loads are L1 broadcasts).
// LDS counters: 64 rows x 37 u32 (2-way bank aliasing = free per m136).
// Self-pair deliberately counted: d=0 -> rel=(3,3) exactly -> cell 21,
// subtracted in k2. Arithmetic (sub, then fma *2+3) is bit-identical to the
// reference's (obs_j-obs_i)/0.5 + 3, incl. NaN masking for free.
// Epilogue: pack 2 cells/u32, plain coalesced stores to partial[jq][agent][18].
// ---------------------------------------------------------------------------
__global__ __launch_bounds__(256) void occ_hist_kernel(
    const float2* __restrict__ obs, unsigned* __restrict__ partial, int jrange) {
  __shared__ unsigned cnt[64 * CSTRIDE];
  const int tid = threadIdx.x;
  for (int k = tid; k < 64 * CSTRIDE; k += 256) cnt[k] = 0u;
  __syncthreads();

  const int lane = tid & 63;
  const int wv   = tid >> 6;
  const int agent = blockIdx.y * 64 + lane;

  const float2 oi = obs[agent];
  const float xi = oi.x, yi = oi.y;
  unsigned* myCnt = &cnt[lane * CSTRIDE];

  const int jbeg = blockIdx.x * jrange + wv * (jrange >> 2);
  const float4* jp = (const float4*)obs + (jbeg >> 1);
  const int nIter = jrange >> 3;  // 2 agents per float4

#pragma unroll 4
  for (int t = 0; t < nIter; ++t) {
    const float4 o2 = jp[t];  // wave-uniform addr -> L1 broadcast
    {
      const float rx = fmaf(o2.x - xi, 2.0f, 3.0f);
      const float ry = fmaf(o2.y - yi, 2.0f, 3.0f);
      if (rx >= 0.0f && rx < 6.0f && ry >= 0.0f && ry < 6.0f)
        atomicAdd(&myCnt[(int)rx * 6 + (int)ry], 1u);
    }
    {
      const float rx = fmaf(o2.z - xi, 2.0f, 3.0f);
      const float ry = fmaf(o2.w - yi, 2.0f, 3.0f);
      if (rx >= 0.0f && rx < 6.0f && ry >= 0.0f && ry < 6.0f)
        atomicAdd(&myCnt[(int)rx * 6 + (int)ry], 1u);
    }
  }
  __syncthreads();

  // pack (2 x u16 per u32; per-chunk counts <= jrange < 65536) + plain stores
  unsigned* gbase = partial +
      ((size_t)blockIdx.x * NAGENT + (size_t)blockIdx.y * 64) * PWORDS;
  for (int k = tid; k < 64 * PWORDS; k += 256) {
    const int a = k / PWORDS, w = k - a * PWORDS;
    const unsigned lo = cnt[a * CSTRIDE + 2 * w];
    const unsigned hi = cnt[a * CSTRIDE + 2 * w + 1];
    gbase[k] = lo | (hi << 16);
  }
}

// ---------------------------------------------------------------------------
// k2: reduce nchunk packed partials (u32 adds; halves can't carry since
// totals <= 8192), unpack to LDS, subtract self (cell 21, clamped at 0 so
// NaN agents' all-zero rows stay zero), then out = occ @ W^T + b.
// 512 blocks x 256 thr; 16 agents/block; thread = (agent, 8 h's).
// W staged in LDS (144B row stride: float4-aligned, <=2-way banks).
// ---------------------------------------------------------------------------
__global__ __launch_bounds__(256) void occ_gemm_kernel(
    const unsigned* __restrict__ partial, const float* __restrict__ W,
    const float* __restrict__ bias, float* __restrict__ out, int nchunk) {
  __shared__ float Wl[HIDDEN * NCELL];
  __shared__ float occ[16 * CSTRIDE];
  const int tid = threadIdx.x;

  const float4* W4 = (const float4*)W;
  float4* Wl4 = (float4*)Wl;
  for (int k = tid; k < HIDDEN * NCELL / 4; k += 256) Wl4[k] = W4[k];

  const int agBase = blockIdx.x * 16;
  for (int k = tid; k < 16 * PWORDS; k += 256) {
    const int a = k / PWORDS, w = k - a * PWORDS;
    const unsigned* p = partial + (size_t)(agBase + a) * PWORDS + w;
    unsigned s = 0;
    for (int c = 0; c < nchunk; ++c) s += p[(size_t)c * NAGENT * PWORDS];
    float lo = (float)(s & 0xFFFFu);
    float hi = (float)(s >> 16);
    if (w == 10) hi = fmaxf(hi - 1.0f, 0.0f);  // cell 21 = word 10 hi: self-pair
    occ[a * CSTRIDE + 2 * w]     = lo;
    occ[a * CSTRIDE + 2 * w + 1] = hi;
  }
  __syncthreads();

  const int a  = tid >> 4;
  const int hg = tid & 15;

  float occf[NCELL];
#pragma unroll
  for (int c = 0; c < NCELL; ++c) occf[c] = occ[a * CSTRIDE + c];

  float acc[8];
#pragma unroll
  for (int k = 0; k < 8; ++k) acc[k] = bias[hg + 16 * k];

#pragma unroll
  for (int c4 = 0; c4 < 9; ++c4) {
#pragma unroll
    for (int k = 0; k < 8; ++k) {
      const float4 w4 = *(const float4*)&Wl[(hg + 16 * k) * NCELL + c4 * 4];
      acc[k] = fmaf(occf[4 * c4 + 0], w4.x, acc[k]);
      acc[k] = fmaf(occf[4 * c4 + 1], w4.y, acc[k]);
      acc[k] = fmaf(occf[4 * c4 + 2], w4.z, acc[k]);
      acc[k] = fmaf(occf[4 * c4 + 3], w4.w, acc[k]);
    }
  }

  float* ob = out + (size_t)(agBase + a) * HIDDEN;
#pragma unroll
  for (int k = 0; k < 8; ++k) ob[hg + 16 * k] = acc[k];
}

extern "C" void kernel_launch(void* const* d_in, const int* in_sizes, int n_in,
                              void* d_out, int out_size, void* d_ws, size_t ws_size,
                              hipStream_t stream) {
  (void)in_sizes; (void)n_in; (void)out_size;
  const float2* obs = (const float2*)d_in[0];
  const float*  W   = (const float*)d_in[1];
  const float*  b   = (const float*)d_in[2];
  float* out = (float*)d_out;
  unsigned* partial = (unsigned*)d_ws;

  // pick largest chunk count fitting the workspace (16 -> 9.4 MB)
  int nchunk = 2;
  for (int c = 16; c >= 2; c >>= 1) {
    if (ws_size >= (size_t)c * NAGENT * PWORDS * sizeof(unsigned)) { nchunk = c; break; }
  }
  const int jrange = NAGENT / nchunk;

  occ_hist_kernel<<<dim3(nchunk, 128), dim3(256), 0, stream>>>(obs, partial, jrange);
  occ_gemm_kernel<<<dim3(512), dim3(256), 0, stream>>>(partial, W, b, out, nchunk);
}

// Round 3
// 90.042 us; speedup vs baseline: 1.1482x; 1.0926x over previous
//
#include <hip/hip_runtime.h>

#define NAGENT 8192
#define NCELL 36
#define HIDDEN 128
#define CSTRIDE 37   // LDS counter row stride: gcd(37,32)=1 -> <=2 lanes/bank (free)
#define PWORDS 18    // packed row: 36 cells as 18 u32 (2 x u16)
#define NCHUNK 16
#define JCHUNK (NAGENT / NCHUNK)  // 512 js per block

// ---------------------------------------------------------------------------
// k1: pairwise occupancy histogram. Grid dim3(NCHUNK, 128).
// blockIdx.y = agent group (64 agents, lane = agent), blockIdx.x = j-chunk.
// The j-chunk (512 float2 = 4 KB) is staged into LDS once; the hot loop has
// ZERO global loads — wave-uniform ds_read_b128 broadcasts (low latency,
// hidden at 32 waves/CU) feed ~13 VALU/point + a predicated no-rtn ds_add
// into a lane-private counter row (stride 37 -> bank-conflict-free).
// rel coords: rx = fma(xj, 2, 3-2*xi). Self-pair lands at ~(3,3) -> cell 21,
// subtracted (clamped) in k2; fma-rounding drift vs reference flips only
// O(10) boundary pairs out of 67M, each worth <=0.8 on the output (thr 8.0).
// Epilogue: pack 2 cells/u32, plain coalesced stores (no global atomics).
// ---------------------------------------------------------------------------
__global__ __launch_bounds__(256) void occ_hist_kernel(
    const float2* __restrict__ obs, unsigned* __restrict__ partial) {
  __shared__ unsigned cnt[64 * CSTRIDE];      // 9472 B
  __shared__ float4 obs_s[JCHUNK / 2];        // 4096 B
  const int tid = threadIdx.x;

  // stage j-chunk: 256 threads x 1 float4 (coalesced, once)
  obs_s[tid] = ((const float4*)obs)[blockIdx.x * (JCHUNK / 2) + tid];
  for (int k = tid; k < 64 * CSTRIDE; k += 256) cnt[k] = 0u;
  __syncthreads();

  const int lane = tid & 63;
  const int wv   = tid >> 6;
  const int agent = blockIdx.y * 64 + lane;

  const float2 oi = obs[agent];
  const float cx = fmaf(oi.x, -2.0f, 3.0f);   // rx = xj*2 + (3 - 2*xi)
  const float cy = fmaf(oi.y, -2.0f, 3.0f);
  unsigned* myCnt = &cnt[lane * CSTRIDE];

  const float4* jp = &obs_s[wv * (JCHUNK / 8)];  // 64 float4 = 128 js per wave
#pragma unroll 8
  for (int t = 0; t < JCHUNK / 8; ++t) {
    const float4 o2 = jp[t];  // wave-uniform LDS broadcast
    {
      const float rx = fmaf(o2.x, 2.0f, cx);
      const float ry = fmaf(o2.y, 2.0f, cy);
      if (rx >= 0.0f && rx < 6.0f && ry >= 0.0f && ry < 6.0f)
        atomicAdd(&myCnt[(int)rx * 6 + (int)ry], 1u);
    }
    {
      const float rx = fmaf(o2.z, 2.0f, cx);
      const float ry = fmaf(o2.w, 2.0f, cy);
      if (rx >= 0.0f && rx < 6.0f && ry >= 0.0f && ry < 6.0f)
        atomicAdd(&myCnt[(int)rx * 6 + (int)ry], 1u);
    }
  }
  __syncthreads();

  // pack (2 x u16 per u32; per-chunk counts <= 512) + plain coalesced stores
  unsigned* gbase = partial +
      ((size_t)blockIdx.x * NAGENT + (size_t)blockIdx.y * 64) * PWORDS;
  for (int k = tid; k < 64 * PWORDS; k += 256) {
    const int a = k / PWORDS, w = k - a * PWORDS;
    gbase[k] = cnt[a * CSTRIDE + 2 * w] | (cnt[a * CSTRIDE + 2 * w + 1] << 16);
  }
}

// ---------------------------------------------------------------------------
// k2: reduce NCHUNK packed partials (u32 adds; u16 halves can't carry since
// totals <= 8192), unpack to LDS, subtract self (cell 21, clamped at 0),
// then out = occ @ W^T + b. 512 blocks x 256 thr; 16 agents/block;
// thread = (agent, 8 h's). W in LDS (144B rows: float4-aligned, <=2-way banks).
// Reduce loop is compile-time unrolled -> 16 independent loads in flight.
// ---------------------------------------------------------------------------
__global__ __launch_bounds__(256) void occ_gemm_kernel(
    const unsigned* __restrict__ partial, const float* __restrict__ W,
    const float* __restrict__ bias, float* __restrict__ out) {
  __shared__ float Wl[HIDDEN * NCELL];
  __shared__ float occ[16 * CSTRIDE];
  const int tid = threadIdx.x;

  const float4* W4 = (const float4*)W;
  float4* Wl4 = (float4*)Wl;
  for (int k = tid; k < HIDDEN * NCELL / 4; k += 256) Wl4[k] = W4[k];

  const int agBase = blockIdx.x * 16;
  for (int k = tid; k < 16 * PWORDS; k += 256) {
    const int a = k / PWORDS, w = k - a * PWORDS;
    const unsigned* p = partial + (size_t)(agBase + a) * PWORDS + w;
    unsigned s = 0;
#pragma unroll
    for (int c = 0; c < NCHUNK; ++c) s += p[(size_t)c * NAGENT * PWORDS];
    float lo = (float)(s & 0xFFFFu);
    float hi = (float)(s >> 16);
    if (w == 10) hi = fmaxf(hi - 1.0f, 0.0f);  // cell 21 = word 10 hi: self-pair
    occ[a * CSTRIDE + 2 * w]     = lo;
    occ[a * CSTRIDE + 2 * w + 1] = hi;
  }
  __syncthreads();

  const int a  = tid >> 4;
  const int hg = tid & 15;

  float occf[NCELL];
#pragma unroll
  for (int c = 0; c < NCELL; ++c) occf[c] = occ[a * CSTRIDE + c];

  float acc[8];
#pragma unroll
  for (int k = 0; k < 8; ++k) acc[k] = bias[hg + 16 * k];

#pragma unroll
  for (int c4 = 0; c4 < 9; ++c4) {
#pragma unroll
    for (int k = 0; k < 8; ++k) {
      const float4 w4 = *(const float4*)&Wl[(hg + 16 * k) * NCELL + c4 * 4];
      acc[k] = fmaf(occf[4 * c4 + 0], w4.x, acc[k]);
      acc[k] = fmaf(occf[4 * c4 + 1], w4.y, acc[k]);
      acc[k] = fmaf(occf[4 * c4 + 2], w4.z, acc[k]);
      acc[k] = fmaf(occf[4 * c4 + 3], w4.w, acc[k]);
    }
  }

  float* ob = out + (size_t)(agBase + a) * HIDDEN;
#pragma unroll
  for (int k = 0; k < 8; ++k) ob[hg + 16 * k] = acc[k];
}

extern "C" void kernel_launch(void* const* d_in, const int* in_sizes, int n_in,
                              void* d_out, int out_size, void* d_ws, size_t ws_size,
                              hipStream_t stream) {
  (void)in_sizes; (void)n_in; (void)out_size; (void)ws_size;
  const float2* obs = (const float2*)d_in[0];
  const float*  W   = (const float*)d_in[1];
  const float*  b   = (const float*)d_in[2];
  float* out = (float*)d_out;
  unsigned* partial = (unsigned*)d_ws;  // 16*8192*18*4 = 9.4 MB of the 256 MiB ws

  occ_hist_kernel<<<dim3(NCHUNK, 128), dim3(256), 0, stream>>>(obs, partial);
  occ_gemm_kernel<<<dim3(512), dim3(256), 0, stream>>>(partial, W, b, out);
}